// Round 1
// baseline (535.032 us; speedup 1.0000x reference)
//
#include <hip/hip_runtime.h>
#include <math.h>

#define BB 4
#define NN 8192
#define DD 16
#define KK 32
#define OO 64

// Kernel 1: per (b,n) point, per o=lane:
//   y1[row,o] = sum_d W[o,d]      * x[b,d,n]
//   cc[row,o] = sum_d (W[o,D+d]-W[o,d]) * x[b,d,n]
__global__ __launch_bounds__(256) void precomp_k(
    const float* __restrict__ x, const float* __restrict__ W,
    float* __restrict__ y1, float* __restrict__ cc)
{
  const int lane = threadIdx.x & 63;
  const int wid  = blockIdx.x * (blockDim.x >> 6) + (threadIdx.x >> 6);
  const int nw   = (gridDim.x * blockDim.x) >> 6;

  float w1[DD], wd[DD];
#pragma unroll
  for (int d = 0; d < DD; ++d) {
    float a  = W[lane * (2 * DD) + d];
    float b2 = W[lane * (2 * DD) + DD + d];
    w1[d] = a;
    wd[d] = b2 - a;
  }

  for (int row = wid; row < BB * NN; row += nw) {
    const float* xp = x + ((size_t)(row >> 13)) * (DD * NN) + (row & (NN - 1));
    float a1 = 0.f, a2 = 0.f;
#pragma unroll
    for (int d = 0; d < DD; ++d) {
      float xv = xp[(size_t)d * NN];
      a1 = fmaf(w1[d], xv, a1);
      a2 = fmaf(wd[d], xv, a2);
    }
    y1[(size_t)row * OO + lane] = a1;
    cc[(size_t)row * OO + lane] = a2;
  }
}

// Kernel 2: KNN (top-32 by squared distance, self included) + fused edge-conv.
// Block = 1024 threads (16 waves), 1 block handles 128 consecutive queries of
// one batch. All 8192 points of the batch staged in LDS as float4 (128 KiB).
// Each wave: sorted top-32 list lives one-element-per-lane in lanes 0..31.
__global__ __launch_bounds__(1024) void knn_k(
    const float* __restrict__ pts_g, const float* __restrict__ y1,
    const float* __restrict__ cc, float* __restrict__ out)
{
  extern __shared__ float4 P[];   // NN entries = 128 KiB
  const int b   = blockIdx.x >> 6;    // 64 blocks per batch
  const int blk = blockIdx.x & 63;

  const float* px = pts_g + (size_t)b * (3 * NN);
  for (int i = threadIdx.x; i < NN; i += 1024) {
    P[i] = make_float4(px[i], px[NN + i], px[2 * NN + i], 0.f);
  }
  __syncthreads();

  const int lane = threadIdx.x & 63;
  const int wv   = threadIdx.x >> 6;  // 0..15

  for (int qi = 0; qi < 8; ++qi) {
    const int n = blk * 128 + wv * 8 + qi;
    const float4 q = P[n];

    float lv = -INFINITY;   // sorted desc neg-dist, lanes 0..31
    int   li = 0;
    float thr = -INFINITY;  // value at lane 31 (the 32nd best)

    for (int j = 0; j < NN / 64; ++j) {
      const int m = j * 64 + lane;
      float4 p = P[m];
      float dx = p.x - q.x, dy = p.y - q.y, dz = p.z - q.z;
      float negd = -fmaf(dz, dz, fmaf(dy, dy, dx * dx));  // 0 for self, <0 else

      unsigned long long imp = __ballot(negd > thr);
      while (imp) {
        const int src = __ffsll(imp) - 1;
        imp &= imp - 1;
        const float v = __shfl(negd, src);
        if (v > thr) {               // uniform branch; thr may have risen
          const int mi = j * 64 + src;
          unsigned long long bal = __ballot(lv > v);
          const int pos = __popcll(bal & 0xffffffffull);
          const float pv = __shfl_up(lv, 1);
          const int   pi = __shfl_up(li, 1);
          if (lane >= pos && lane < 32) {
            lv = (lane == pos) ? v  : pv;
            li = (lane == pos) ? mi : pi;
          }
          thr = __shfl(lv, 31);
        }
      }
    }

    // Fused conv epilogue: lane = output channel o.
    const size_t rq = (size_t)b * NN + n;
    const float cv = cc[rq * OO + lane];
    float acc = 0.f;
#pragma unroll
    for (int k = 0; k < KK; ++k) {
      const int mk = __shfl(li, k);
      const float t = y1[((size_t)b * NN + mk) * OO + lane] + cv;
      acc += (t >= 0.f) ? t : 0.2f * t;
    }
    out[(size_t)b * (OO * NN) + (size_t)lane * NN + n] = acc * (1.f / 32.f);
  }
}

extern "C" void kernel_launch(void* const* d_in, const int* in_sizes, int n_in,
                              void* d_out, int out_size, void* d_ws, size_t ws_size,
                              hipStream_t stream) {
  const float* points = (const float*)d_in[0];
  const float* x      = (const float*)d_in[1];
  const float* W      = (const float*)d_in[2];
  float* out = (float*)d_out;

  float* y1 = (float*)d_ws;                      // B*N*O floats = 8 MB
  float* cc = y1 + (size_t)BB * NN * OO;         // B*N*O floats = 8 MB

  hipLaunchKernelGGL(precomp_k, dim3(256), dim3(256), 0, stream, x, W, y1, cc);
  hipLaunchKernelGGL(knn_k, dim3(256), dim3(1024), NN * sizeof(float4), stream,
                     points, y1, cc, out);
}

// Round 2
// 451.324 us; speedup vs baseline: 1.1855x; 1.1855x over previous
//
#include <hip/hip_runtime.h>
#include <math.h>

#define BB 4
#define NN 8192
#define DD 16
#define KK 32
#define OO 64

// Kernel 1: per (b,n) point, per o=lane:
//   y1[row,o] = sum_d W[o,d]      * x[b,d,n]
//   cc[row,o] = sum_d (W[o,D+d]-W[o,d]) * x[b,d,n]
__global__ __launch_bounds__(256) void precomp_k(
    const float* __restrict__ x, const float* __restrict__ W,
    float* __restrict__ y1, float* __restrict__ cc)
{
  const int lane = threadIdx.x & 63;
  const int wid  = blockIdx.x * (blockDim.x >> 6) + (threadIdx.x >> 6);
  const int nw   = (gridDim.x * blockDim.x) >> 6;

  float w1[DD], wd[DD];
#pragma unroll
  for (int d = 0; d < DD; ++d) {
    float a  = W[lane * (2 * DD) + d];
    float b2 = W[lane * (2 * DD) + DD + d];
    w1[d] = a;
    wd[d] = b2 - a;
  }

  for (int row = wid; row < BB * NN; row += nw) {
    const float* xp = x + ((size_t)(row >> 13)) * (DD * NN) + (row & (NN - 1));
    float a1 = 0.f, a2 = 0.f;
#pragma unroll
    for (int d = 0; d < DD; ++d) {
      float xv = xp[(size_t)d * NN];
      a1 = fmaf(w1[d], xv, a1);
      a2 = fmaf(wd[d], xv, a2);
    }
    y1[(size_t)row * OO + lane] = a1;
    cc[(size_t)row * OO + lane] = a2;
  }
}

// Kernel 2: KNN (top-32 smallest squared distance, self included) + fused conv.
// Block = 1024 threads (16 waves), handles 128 consecutive queries of one
// batch; all 8192 points staged in LDS as float4 (128 KiB).
//
// Top-32 list: rank-tracked UNSORTED set in lanes 0..31 — each lane holds
// (lv = distance, li = index, ri = rank). Insertion moves NO data across
// lanes: ranks shift arithmetically, the rank-31 (worst) lane swaps in the
// new element. All cross-lane traffic is v_readlane / ballot (VALU+SALU),
// zero DS-pipe ops — the only LDS op per 64 candidates is one ds_read_b128.
__global__ __launch_bounds__(1024) void knn_k(
    const float* __restrict__ pts_g, const float* __restrict__ y1,
    const float* __restrict__ cc, float* __restrict__ out)
{
  extern __shared__ float4 P[];   // NN entries = 128 KiB
  const int b   = blockIdx.x >> 6;    // 64 blocks per batch
  const int blk = blockIdx.x & 63;

  const float* px = pts_g + (size_t)b * (3 * NN);
  for (int i = threadIdx.x; i < NN; i += 1024) {
    P[i] = make_float4(px[i], px[NN + i], px[2 * NN + i], 0.f);
  }
  __syncthreads();

  const int lane = threadIdx.x & 63;
  const int wv   = threadIdx.x >> 6;  // 0..15

  for (int qi = 0; qi < 8; ++qi) {
    const int n = blk * 128 + wv * 8 + qi;
    const float4 q = P[n];

    float lv = INFINITY;              // list value (squared distance)
    int   li = 0;                     // list index
    int   ri = (lane < 32) ? lane : 64;  // list rank (0 = best, 31 = worst)
    float thr = INFINITY;             // current 32nd-smallest distance

    for (int j = 0; j < NN / 64; ++j) {
      const int m = j * 64 + lane;
      float4 p = P[m];
      float dx = p.x - q.x, dy = p.y - q.y, dz = p.z - q.z;
      float d = fmaf(dz, dz, fmaf(dy, dy, dx * dx));   // 0 for self

      unsigned long long imp = __ballot(d < thr);
      while (imp) {
        const int src = __ffsll(imp) - 1;
        imp &= imp - 1;
        const unsigned vu = (unsigned)__builtin_amdgcn_readlane(
            (int)__float_as_uint(d), src);
        // positive floats: IEEE bit pattern is monotone -> uint compare
        if (vu < __float_as_uint(thr)) {
          const float v  = __uint_as_float(vu);
          const int   mi = j * 64 + src;
          // rank of new element = count of entries <= v (stable w.r.t. index)
          unsigned long long bal = __ballot(lv <= v);
          const int pos = __popcll(bal & 0xffffffffull);
          const bool evict = (ri == 31);
          ri += (ri >= pos) ? 1 : 0;
          if (evict) { ri = pos; lv = v; li = mi; }
          // new threshold = value of the (new) rank-31 holder
          unsigned long long b31 = __ballot(ri == 31);
          const int l31 = __ffsll(b31) - 1;
          thr = __uint_as_float((unsigned)__builtin_amdgcn_readlane(
              (int)__float_as_uint(lv), l31));
        }
      }
    }

    // Fused conv epilogue: lane = output channel o. Order of k irrelevant
    // (sum over k). readlane(li, k) with constant k -> VALU, no DS.
    const size_t rq = (size_t)b * NN + n;
    const float cv = cc[rq * OO + lane];
    float acc = 0.f;
#pragma unroll
    for (int k = 0; k < KK; ++k) {
      const int mk = __builtin_amdgcn_readlane(li, k);
      const float t = y1[((size_t)b * NN + mk) * OO + lane] + cv;
      acc += (t >= 0.f) ? t : 0.2f * t;
    }
    out[(size_t)b * (OO * NN) + (size_t)lane * NN + n] = acc * (1.f / 32.f);
  }
}

extern "C" void kernel_launch(void* const* d_in, const int* in_sizes, int n_in,
                              void* d_out, int out_size, void* d_ws, size_t ws_size,
                              hipStream_t stream) {
  const float* points = (const float*)d_in[0];
  const float* x      = (const float*)d_in[1];
  const float* W      = (const float*)d_in[2];
  float* out = (float*)d_out;

  float* y1 = (float*)d_ws;                      // B*N*O floats = 8 MB
  float* cc = y1 + (size_t)BB * NN * OO;         // B*N*O floats = 8 MB

  hipLaunchKernelGGL(precomp_k, dim3(512), dim3(256), 0, stream, x, W, y1, cc);
  hipLaunchKernelGGL(knn_k, dim3(256), dim3(1024), NN * sizeof(float4), stream,
                     points, y1, cc, out);
}

// Round 3
// 373.324 us; speedup vs baseline: 1.4332x; 1.2089x over previous
//
#include <hip/hip_runtime.h>
#include <math.h>

#define BB 4
#define NN 8192
#define DD 16
#define KK 32
#define OO 64
#define HALF 4096
#define QPW 4   // queries per wave (persistent top-32 lists)

// Kernel 1: per (b,n) point, per o=lane:
//   y1[row,o] = sum_d W[o,d]      * x[b,d,n]
//   cc[row,o] = sum_d (W[o,D+d]-W[o,d]) * x[b,d,n]
__global__ __launch_bounds__(256) void precomp_k(
    const float* __restrict__ x, const float* __restrict__ W,
    float* __restrict__ y1, float* __restrict__ cc)
{
  const int lane = threadIdx.x & 63;
  const int wid  = blockIdx.x * (blockDim.x >> 6) + (threadIdx.x >> 6);
  const int nw   = (gridDim.x * blockDim.x) >> 6;

  float w1[DD], wd[DD];
#pragma unroll
  for (int d = 0; d < DD; ++d) {
    float a  = W[lane * (2 * DD) + d];
    float b2 = W[lane * (2 * DD) + DD + d];
    w1[d] = a;
    wd[d] = b2 - a;
  }

  for (int row = wid; row < BB * NN; row += nw) {
    const float* xp = x + ((size_t)(row >> 13)) * (DD * NN) + (row & (NN - 1));
    float a1 = 0.f, a2 = 0.f;
#pragma unroll
    for (int d = 0; d < DD; ++d) {
      float xv = xp[(size_t)d * NN];
      a1 = fmaf(w1[d], xv, a1);
      a2 = fmaf(wd[d], xv, a2);
    }
    y1[(size_t)row * OO + lane] = a1;
    cc[(size_t)row * OO + lane] = a2;
  }
}

// Kernel 2: KNN top-32 (squared distance, self included) + fused edge-conv.
// 512 blocks x 1024 threads. Each block: 64 consecutive queries of one batch.
// Points staged in LDS in TWO 4096-point halves (64 KiB) -> 2 blocks/CU,
// 8 waves/SIMD. Each wave maintains QPW=4 persistent rank-tracked top-32
// lists (lanes 0..31 hold one (value,index,rank) entry per query); one
// ds_read_b128 per 64-candidate chunk serves all 4 queries. Candidate visit
// order is global index order -> decisions identical to previous rounds.
__global__ __launch_bounds__(1024, 8) void knn_k(
    const float* __restrict__ pts_g, const float* __restrict__ y1,
    const float* __restrict__ cc, float* __restrict__ out)
{
  __shared__ float4 P[HALF];          // 64 KiB
  const int b   = blockIdx.x >> 7;    // 128 blocks per batch
  const int blk = blockIdx.x & 127;
  const float* px = pts_g + (size_t)b * (3 * NN);

  const int lane = threadIdx.x & 63;
  const int wv   = threadIdx.x >> 6;  // 0..15
  const int q0   = blk * 64 + wv * QPW;

  // Query coords, hoisted to scalar regs (wave-uniform).
  float qx[QPW], qy[QPW], qz[QPW];
#pragma unroll
  for (int i = 0; i < QPW; ++i) {
    const int n = q0 + i;
    qx[i] = __uint_as_float((unsigned)__builtin_amdgcn_readfirstlane(
        (int)__float_as_uint(px[n])));
    qy[i] = __uint_as_float((unsigned)__builtin_amdgcn_readfirstlane(
        (int)__float_as_uint(px[NN + n])));
    qz[i] = __uint_as_float((unsigned)__builtin_amdgcn_readfirstlane(
        (int)__float_as_uint(px[2 * NN + n])));
  }

  float lv[QPW];   // list value (squared distance), lanes 0..31
  int   li[QPW];   // list index
  int   ri[QPW];   // list rank (0 best .. 31 worst); lanes>=32 park at 64+
  float thr[QPW];  // current 32nd-smallest (wave-uniform -> SGPR)
#pragma unroll
  for (int i = 0; i < QPW; ++i) {
    lv[i] = INFINITY; li[i] = 0; ri[i] = (lane < 32) ? lane : 64;
    thr[i] = INFINITY;
  }

#pragma unroll 1
  for (int half = 0; half < 2; ++half) {
    const int base = half * HALF;
    __syncthreads();                  // previous half fully consumed
    for (int i = threadIdx.x; i < HALF; i += 1024) {
      const int g = base + i;
      P[i] = make_float4(px[g], px[NN + g], px[2 * NN + g], 0.f);
    }
    __syncthreads();

#pragma unroll 1
    for (int j = 0; j < HALF / 64; ++j) {
      const float4 p = P[j * 64 + lane];
#pragma unroll
      for (int qq = 0; qq < QPW; ++qq) {
        const float dx = p.x - qx[qq], dy = p.y - qy[qq], dz = p.z - qz[qq];
        const float d = fmaf(dz, dz, fmaf(dy, dy, dx * dx)); // 0 for self
        unsigned long long imp = __ballot(d < thr[qq]);
        while (imp) {
          const int src = __ffsll(imp) - 1;
          imp &= imp - 1;
          const unsigned vu = (unsigned)__builtin_amdgcn_readlane(
              (int)__float_as_uint(d), src);
          // positive floats: IEEE bits are monotone -> uint compare
          if (vu < __float_as_uint(thr[qq])) {
            const float v  = __uint_as_float(vu);
            const int   mi = base + j * 64 + src;
            unsigned long long bal = __ballot(lv[qq] <= v);
            const int pos = __popcll(bal & 0xffffffffull);
            const bool evict = (ri[qq] == 31);
            ri[qq] += (ri[qq] >= pos) ? 1 : 0;
            if (evict) { ri[qq] = pos; lv[qq] = v; li[qq] = mi; }
            unsigned long long b31 = __ballot(ri[qq] == 31);
            const int l31 = __ffsll(b31) - 1;
            thr[qq] = __uint_as_float((unsigned)__builtin_amdgcn_readlane(
                (int)__float_as_uint(lv[qq]), l31));
          }
        }
      }
    }
  }

  // Fused conv epilogue: lane = output channel o; k-order irrelevant (sum).
#pragma unroll 1
  for (int qq = 0; qq < QPW; ++qq) {
    const int n = q0 + qq;
    const size_t rq = (size_t)b * NN + n;
    const float cv = cc[rq * OO + lane];
    float acc = 0.f;
#pragma unroll
    for (int k = 0; k < KK; ++k) {
      const int mk = __builtin_amdgcn_readlane(li[qq], k);
      const float t = y1[((size_t)b * NN + mk) * OO + lane] + cv;
      acc += (t >= 0.f) ? t : 0.2f * t;
    }
    out[(size_t)b * (OO * NN) + (size_t)lane * NN + n] = acc * (1.f / 32.f);
  }
}

extern "C" void kernel_launch(void* const* d_in, const int* in_sizes, int n_in,
                              void* d_out, int out_size, void* d_ws, size_t ws_size,
                              hipStream_t stream) {
  const float* points = (const float*)d_in[0];
  const float* x      = (const float*)d_in[1];
  const float* W      = (const float*)d_in[2];
  float* out = (float*)d_out;

  float* y1 = (float*)d_ws;                      // B*N*O floats = 8 MB
  float* cc = y1 + (size_t)BB * NN * OO;         // B*N*O floats = 8 MB

  hipLaunchKernelGGL(precomp_k, dim3(512), dim3(256), 0, stream, x, W, y1, cc);
  hipLaunchKernelGGL(knn_k, dim3(512), dim3(1024), 0, stream,
                     points, y1, cc, out);
}